// Round 7
// baseline (181.172 us; speedup 1.0000x reference)
//
#include <hip/hip_runtime.h>

#define H_DIM 1024
#define I_DIM 512
#define E_EXP 16
#define BM    64
#define BK    64
#define BSTR  68   // Bs row stride in shorts (64 + 4 pad -> 34 dwords, rows hit distinct banks)

using bf16x8   = __attribute__((ext_vector_type(8))) short;
using floatx4  = __attribute__((ext_vector_type(4))) float;
using ushort4v = __attribute__((ext_vector_type(4))) unsigned short;

__device__ __forceinline__ unsigned short f2bf(float f) {
  union { float f; unsigned u; } v; v.f = f;
  return (unsigned short)((v.u + 0x7FFFu + ((v.u >> 16) & 1u)) >> 16);  // RNE
}
__device__ __forceinline__ unsigned pk2(float a, float b) {
  return (unsigned)f2bf(a) | ((unsigned)f2bf(b) << 16);
}

__device__ __forceinline__ void gld16(const void* g, void* l) {
  __builtin_amdgcn_global_load_lds((const __attribute__((address_space(1))) void*)g,
                                   (__attribute__((address_space(3))) void*)l,
                                   16, 0, 0);
}

// barrier draining LDS ops only (vmem prefetch stays in flight)
__device__ __forceinline__ void bar_lgkm() {
  asm volatile("s_waitcnt lgkmcnt(0)" ::: "memory");
  __builtin_amdgcn_sched_barrier(0);
  __builtin_amdgcn_s_barrier();
  __builtin_amdgcn_sched_barrier(0);
}
// full drain — once per K-step
__device__ __forceinline__ void bar_full() {
  asm volatile("s_waitcnt vmcnt(0) lgkmcnt(0)" ::: "memory");
  __builtin_amdgcn_sched_barrier(0);
  __builtin_amdgcn_s_barrier();
  __builtin_amdgcn_sched_barrier(0);
}

__device__ __forceinline__ bool tile_info(const int* __restrict__ counts, int by,
                                          int& e, int& row0, int& base, int& cnt) {
  int acc = 0, off = 0;
  e = -1;
  #pragma unroll
  for (int i = 0; i < E_EXP; ++i) {
    int c = counts[i];
    int nt = (c + BM - 1) >> 6;          // 64-row tiles
    if (e < 0 && by < acc + nt) { e = i; row0 = (by - acc) * BM; base = off; cnt = c; }
    acc += nt; off += c;
  }
  return e >= 0;
}

// ---------------- x: fp32 -> bf16 (streaming) ----------------
__global__ void k_cvt(const float* __restrict__ x, unsigned short* __restrict__ xb) {
  const float4* s4 = (const float4*)x;
  int b0 = blockIdx.x * 512 + threadIdx.x;
  float4 a = s4[b0];
  float4 b = s4[b0 + 256];
  ushort4v oa, ob;
  oa.x = f2bf(a.x); oa.y = f2bf(a.y); oa.z = f2bf(a.z); oa.w = f2bf(a.w);
  ob.x = f2bf(b.x); ob.y = f2bf(b.y); ob.z = f2bf(b.z); ob.w = f2bf(b.w);
  ((ushort4v*)xb)[b0] = oa;
  ((ushort4v*)xb)[b0 + 256] = ob;
}

// ---------------- GEMM A: h = silu(x@Wg)*(x@Wu) ----------------
// BM=64 tiles -> grid (16,80) = 1280 blocks, 25088 B LDS -> 6 blocks/CU.
// Proven round-4 schedule: loadB(regs)+loadA(gld16) -> compute -> bar_lgkm ->
// convert+write Bs -> bar_full. TLP (5-6 blocks/CU) hides the staging latency.
__launch_bounds__(256, 6)
__global__ void k_gemm_a(const unsigned short* __restrict__ xb,
                         const float* __restrict__ wgu,
                         unsigned short* __restrict__ hb,
                         const int* __restrict__ counts) {
  __shared__ unsigned short As[2][BM * BK];   // 2 x 8 KB
  __shared__ unsigned short Bs[64 * BSTR];    // 8.7 KB; rows 0-31 g, 32-63 u

  int e, row0, base, cnt;
  if (!tile_info(counts, blockIdx.y, e, row0, base, cnt)) return;
  const int rows = (cnt - row0 < BM) ? (cnt - row0) : BM;
  const int c0 = blockIdx.x * 32;

  const int tid = threadIdx.x;
  const int w = tid >> 6, l = tid & 63;
  const int lr = l & 15, q = l >> 4;
  const int asr = l >> 3;                     // A staging: LDS slot row in 8-row group
  const int akc = ((l & 7) ^ asr) * 8;        // XOR-swizzled global 16B chunk (shorts)
  const int cswz = lr & 7;                    // A read-side swizzle key

  // B staging: thread owns 4 cols (f4) of g-or-u (seg), k rows kb..kb+3
  const int f4  = tid & 7;
  const int seg = (tid >> 3) & 1;
  const int kb  = (tid >> 4) * 4;             // 0..60
  const float* gptr = wgu + (size_t)e * H_DIM * (2 * I_DIM) + c0 + f4 * 4 + seg * I_DIM;
  unsigned int* BsD = (unsigned int*)Bs;
  const int bd0 = (seg * 32 + f4 * 4) * (BSTR / 2) + (kb >> 1);

  const int mhalf = w & 1, nhalf = w >> 1;
  const int mrow = mhalf * 32;
  const unsigned short* arow = xb + (size_t)(base + row0) * H_DIM;

  int agr[2];
  #pragma unroll
  for (int t = 0; t < 2; ++t) {
    int r = w * 16 + t * 8 + asr;
    agr[t] = (r < rows) ? r : rows - 1;
  }

  floatx4 accg[2], accu[2];
  #pragma unroll
  for (int i = 0; i < 2; ++i) { accg[i] = (floatx4){0,0,0,0}; accu[i] = (floatx4){0,0,0,0}; }

  float4 bv[4];

  auto loadB = [&](int kk) {
    #pragma unroll
    for (int j = 0; j < 4; ++j)
      bv[j] = *(const float4*)&gptr[(size_t)(kk + kb + j) * (2 * I_DIM)];
  };
  auto loadA = [&](int kk, int buf) {
    #pragma unroll
    for (int t = 0; t < 2; ++t)
      gld16(&arow[(size_t)agr[t] * H_DIM + kk + akc], &As[buf][(w * 16 + t * 8) * BK]);
  };
  auto writeB = [&]() {
    #pragma unroll
    for (int c = 0; c < 4; ++c) {
      uint2 d;
      d.x = pk2(bv[0][c], bv[1][c]);
      d.y = pk2(bv[2][c], bv[3][c]);
      *(uint2*)&BsD[bd0 + c * (BSTR / 2)] = d;
    }
  };
  auto compute = [&](int cb) {
    #pragma unroll
    for (int kf = 0; kf < 2; ++kf) {
      const int c = kf * 4 + q;
      const int ca = (c ^ cswz) * 8;          // swizzled A chunk
      const int ch = c * 8;                   // linear B chunk (padded rows)
      bf16x8 af[2], bg, bu;
      #pragma unroll
      for (int mi = 0; mi < 2; ++mi)
        af[mi] = *(const bf16x8*)&As[cb][(mrow + mi * 16 + lr) * BK + ca];
      bg = *(const bf16x8*)&Bs[(nhalf * 16 + lr) * BSTR + ch];
      bu = *(const bf16x8*)&Bs[(32 + nhalf * 16 + lr) * BSTR + ch];
      #pragma unroll
      for (int mi = 0; mi < 2; ++mi) {
        accg[mi] = __builtin_amdgcn_mfma_f32_16x16x32_bf16(af[mi], bg, accg[mi], 0, 0, 0);
        accu[mi] = __builtin_amdgcn_mfma_f32_16x16x32_bf16(af[mi], bu, accu[mi], 0, 0, 0);
      }
    }
  };

  // prologue: stage tile 0
  loadB(0);
  loadA(0, 0);
  writeB();
  __syncthreads();

  const int nk = H_DIM / BK;   // 16
  int cur = 0;
  for (int ki = 0; ki < nk - 1; ++ki) {
    const int kk = (ki + 1) * BK;
    loadB(kk);                  // 4 coalesced float4 loads
    loadA(kk, cur ^ 1);         // 2 gld16 -> other buffer
    __builtin_amdgcn_sched_barrier(0);
    compute(cur);
    bar_lgkm();                 // Bs readers done; prefetch still flying
    writeB();                   // counted vmcnt wait for bv only
    bar_full();
    cur ^= 1;
  }
  compute(cur);                 // tail

  #pragma unroll
  for (int mi = 0; mi < 2; ++mi)
    #pragma unroll
    for (int r = 0; r < 4; ++r) {
      int row_local = mrow + mi * 16 + q * 4 + r;
      if (row_local >= rows) continue;
      size_t orow = (size_t)(base + row0 + row_local) * I_DIM;
      float g = accg[mi][r], u = accu[mi][r];
      float s = g / (1.0f + __expf(-g)) * u;
      hb[orow + c0 + nhalf * 16 + lr] = f2bf(s);
    }
}

// ---------------- GEMM B: out = h @ Wd ----------------
// BM=64 x 64-col tiles -> grid (16,80) = 1280 blocks, 6 blocks/CU.
__launch_bounds__(256, 6)
__global__ void k_gemm_b(const unsigned short* __restrict__ hb,
                         const float* __restrict__ wdn,
                         float* __restrict__ out,
                         const int* __restrict__ counts) {
  __shared__ unsigned short As[2][BM * BK];
  __shared__ unsigned short Bs[64 * BSTR];

  int e, row0, base, cnt;
  if (!tile_info(counts, blockIdx.y, e, row0, base, cnt)) return;
  const int rows = (cnt - row0 < BM) ? (cnt - row0) : BM;
  const int n0 = blockIdx.x * 64;

  const int tid = threadIdx.x;
  const int w = tid >> 6, l = tid & 63;
  const int lr = l & 15, q = l >> 4;
  const int asr = l >> 3;
  const int akc = ((l & 7) ^ asr) * 8;
  const int cswz = lr & 7;

  const int f4 = tid & 15;                    // 4-col chunk within 64
  const int kb = (tid >> 4) * 4;              // 0..60
  const float* gptr = wdn + (size_t)e * I_DIM * H_DIM + n0 + f4 * 4;
  unsigned int* BsD = (unsigned int*)Bs;
  const int bd0 = (f4 * 4) * (BSTR / 2) + (kb >> 1);

  const int mhalf = w & 1, nhalf = w >> 1;
  const int mrow = mhalf * 32;
  const unsigned short* arow = hb + (size_t)(base + row0) * I_DIM;

  int agr[2];
  #pragma unroll
  for (int t = 0; t < 2; ++t) {
    int r = w * 16 + t * 8 + asr;
    agr[t] = (r < rows) ? r : rows - 1;
  }

  floatx4 acc[2][2];
  #pragma unroll
  for (int i = 0; i < 2; ++i)
    #pragma unroll
    for (int j = 0; j < 2; ++j) acc[i][j] = (floatx4){0,0,0,0};

  float4 bv[4];

  auto loadB = [&](int kk) {
    #pragma unroll
    for (int j = 0; j < 4; ++j)
      bv[j] = *(const float4*)&gptr[(size_t)(kk + kb + j) * H_DIM];
  };
  auto loadA = [&](int kk, int buf) {
    #pragma unroll
    for (int t = 0; t < 2; ++t)
      gld16(&arow[(size_t)agr[t] * I_DIM + kk + akc], &As[buf][(w * 16 + t * 8) * BK]);
  };
  auto writeB = [&]() {
    #pragma unroll
    for (int c = 0; c < 4; ++c) {
      uint2 d;
      d.x = pk2(bv[0][c], bv[1][c]);
      d.y = pk2(bv[2][c], bv[3][c]);
      *(uint2*)&BsD[bd0 + c * (BSTR / 2)] = d;
    }
  };
  auto compute = [&](int cb) {
    #pragma unroll
    for (int kf = 0; kf < 2; ++kf) {
      const int c = kf * 4 + q;
      const int ca = (c ^ cswz) * 8;
      const int ch = c * 8;
      bf16x8 af[2], bf[2];
      #pragma unroll
      for (int mi = 0; mi < 2; ++mi)
        af[mi] = *(const bf16x8*)&As[cb][(mrow + mi * 16 + lr) * BK + ca];
      #pragma unroll
      for (int ni = 0; ni < 2; ++ni)
        bf[ni] = *(const bf16x8*)&Bs[(nhalf * 32 + ni * 16 + lr) * BSTR + ch];
      #pragma unroll
      for (int mi = 0; mi < 2; ++mi)
        #pragma unroll
        for (int ni = 0; ni < 2; ++ni)
          acc[mi][ni] = __builtin_amdgcn_mfma_f32_16x16x32_bf16(af[mi], bf[ni], acc[mi][ni], 0, 0, 0);
    }
  };

  loadB(0);
  loadA(0, 0);
  writeB();
  __syncthreads();

  const int nk = I_DIM / BK;   // 8
  int cur = 0;
  for (int ki = 0; ki < nk - 1; ++ki) {
    const int kk = (ki + 1) * BK;
    loadB(kk);
    loadA(kk, cur ^ 1);
    __builtin_amdgcn_sched_barrier(0);
    compute(cur);
    bar_lgkm();
    writeB();
    bar_full();
    cur ^= 1;
  }
  compute(cur);

  #pragma unroll
  for (int mi = 0; mi < 2; ++mi)
    #pragma unroll
    for (int r = 0; r < 4; ++r) {
      int row_local = mrow + mi * 16 + q * 4 + r;
      if (row_local >= rows) continue;
      size_t orow = (size_t)(base + row0 + row_local) * H_DIM;
      #pragma unroll
      for (int ni = 0; ni < 2; ++ni)
        out[orow + n0 + nhalf * 32 + ni * 16 + lr] = acc[mi][ni][r];
    }
}

// ---------------- launch ----------------
extern "C" void kernel_launch(void* const* d_in, const int* in_sizes, int n_in,
                              void* d_out, int out_size, void* d_ws, size_t ws_size,
                              hipStream_t stream) {
  const float* x      = (const float*)d_in[0];
  const float* wgu    = (const float*)d_in[1];
  const float* wdn    = (const float*)d_in[2];
  const int*   counts = (const int*)d_in[3];
  float* out = (float*)d_out;

  unsigned char* ws = (unsigned char*)d_ws;
  unsigned short* xb = (unsigned short*)(ws);            // 8 MB
  unsigned short* hb = (unsigned short*)(ws + 8388608);  // 4 MB

  k_cvt<<<2048, 256, 0, stream>>>(x, xb);
  // y-slots: sum ceil(c_e/64) <= 4096/64 + 16 = 80
  k_gemm_a<<<dim3(I_DIM / 32, 80), 256, 0, stream>>>(xb, wgu, hb, counts);   // 1280 blocks
  k_gemm_b<<<dim3(H_DIM / 64, 80), 256, 0, stream>>>(hb, wdn, out, counts);  // 1280 blocks
}

// Round 8
// 172.452 us; speedup vs baseline: 1.0506x; 1.0506x over previous
//
#include <hip/hip_runtime.h>

#define H_DIM 1024
#define I_DIM 512
#define E_EXP 16
#define BM    128
#define BK    64
// Bs: zero-pad stride (64 shorts); bank spread via KEY(r) = (r&7)^((r>>3)&3)
// chunk-XOR applied on BOTH write and read (write: 8 distinct banks/16 lanes,
// read: 2-way max — verified for both GEMM fragment maps).

#define KEY(r) (((r) & 7) ^ (((r) >> 3) & 3))

using bf16x8   = __attribute__((ext_vector_type(8))) short;
using floatx4  = __attribute__((ext_vector_type(4))) float;
using ushort4v = __attribute__((ext_vector_type(4))) unsigned short;

__device__ __forceinline__ unsigned short f2bf(float f) {
  union { float f; unsigned u; } v; v.f = f;
  return (unsigned short)((v.u + 0x7FFFu + ((v.u >> 16) & 1u)) >> 16);  // RNE
}
__device__ __forceinline__ unsigned pk2(float a, float b) {
  return (unsigned)f2bf(a) | ((unsigned)f2bf(b) << 16);
}

__device__ __forceinline__ void gld16(const void* g, void* l) {
  __builtin_amdgcn_global_load_lds((const __attribute__((address_space(1))) void*)g,
                                   (__attribute__((address_space(3))) void*)l,
                                   16, 0, 0);
}

// step barrier: drain the 4 A-stage gld16 (oldest after stB's implicit wait),
// keep the 4 newest B-prefetch loads in flight; make LDS writes visible.
__device__ __forceinline__ void bar_v4() {
  asm volatile("s_waitcnt vmcnt(4) lgkmcnt(0)" ::: "memory");
  __builtin_amdgcn_sched_barrier(0);
  __builtin_amdgcn_s_barrier();
  __builtin_amdgcn_sched_barrier(0);
}
__device__ __forceinline__ void bar_v0() {
  asm volatile("s_waitcnt vmcnt(0) lgkmcnt(0)" ::: "memory");
  __builtin_amdgcn_sched_barrier(0);
  __builtin_amdgcn_s_barrier();
  __builtin_amdgcn_sched_barrier(0);
}

__device__ __forceinline__ bool tile_info(const int* __restrict__ counts, int by,
                                          int& e, int& row0, int& base, int& cnt) {
  int acc = 0, off = 0;
  e = -1;
  #pragma unroll
  for (int i = 0; i < E_EXP; ++i) {
    int c = counts[i];
    int nt = (c + BM - 1) >> 7;
    if (e < 0 && by < acc + nt) { e = i; row0 = (by - acc) * BM; base = off; cnt = c; }
    acc += nt; off += c;
  }
  return e >= 0;
}

// ---------------- x: fp32 -> bf16 (streaming) ----------------
__global__ void k_cvt(const float* __restrict__ x, unsigned short* __restrict__ xb) {
  const float4* s4 = (const float4*)x;
  int b0 = blockIdx.x * 512 + threadIdx.x;
  float4 a = s4[b0];
  float4 b = s4[b0 + 256];
  ushort4v oa, ob;
  oa.x = f2bf(a.x); oa.y = f2bf(a.y); oa.z = f2bf(a.z); oa.w = f2bf(a.w);
  ob.x = f2bf(b.x); ob.y = f2bf(b.y); ob.z = f2bf(b.z); ob.w = f2bf(b.w);
  ((ushort4v*)xb)[b0] = oa;
  ((ushort4v*)xb)[b0 + 256] = ob;
}

// ---------------- GEMM A: h = silu(x@Wg)*(x@Wu) ----------------
// BM=128, 32 gu-cols/block, grid (16,48). Single barrier per K-step:
//   loadA(t+1)->As[nxt] (gld16); stB(t+1 <- regs from step t-1); loadB(t+2)->regs;
//   compute(t); vmcnt(4)+lgkm(0)+barrier.
// B raw loads fly a full step (~1500cy > 900cy HBM); vmcnt never drains to 0.
__launch_bounds__(256, 3)
__global__ void k_gemm_a(const unsigned short* __restrict__ xb,
                         const float* __restrict__ wgu,
                         unsigned short* __restrict__ hb,
                         const int* __restrict__ counts) {
  __shared__ unsigned short As[2][BM * BK];   // 32 KB
  __shared__ unsigned short Bs[2][64 * BK];   // 16 KB; rows 0-31 g, 32-63 u

  int e, row0, base, cnt;
  if (!tile_info(counts, blockIdx.y, e, row0, base, cnt)) return;
  const int rows = (cnt - row0 < BM) ? (cnt - row0) : BM;
  const int c0 = blockIdx.x * 32;

  const int tid = threadIdx.x;
  const int w = tid >> 6, l = tid & 63;
  const int lr = l & 15, q = l >> 4;
  const int asr = l >> 3;                     // A staging: LDS slot row in 8-row group
  const int akc = ((l & 7) ^ asr) * 8;        // XOR-swizzled global 16B chunk (A)
  const int cswz = lr & 7;                    // A read key (= row&7 for A rows)

  // B staging: thread owns 4 cols (f4) of g-or-u (seg), k rows kb..kb+3
  const int f4  = tid & 7;
  const int seg = (tid >> 3) & 1;
  const int kb  = (tid >> 4) * 4;             // 0..60
  const int rb0 = seg * 32 + f4 * 4;
  const float* gptr = wgu + (size_t)e * H_DIM * (2 * I_DIM) + c0 + f4 * 4 + seg * I_DIM;
  const int cwk = kb >> 3;                    // k-chunk this thread writes
  const int din = (kb >> 1) & 3;              // dword pair within chunk (0 or 2)

  const int mhalf = w & 1, nhalf = w >> 1;
  const int mrow = mhalf * 64;
  const unsigned short* arow = xb + (size_t)(base + row0) * H_DIM;

  // B read keys (KEY(row+32)==KEY(row) since +32 ≡ 0 mod (8 and the >>3&3 field))
  const int rg = nhalf * 16 + lr;
  const int keyB = KEY(rg);

  int agr[4];
  #pragma unroll
  for (int t = 0; t < 4; ++t) {
    int r = w * 32 + t * 8 + asr;
    agr[t] = (r < rows) ? r : rows - 1;
  }

  floatx4 accg[4], accu[4];
  #pragma unroll
  for (int i = 0; i < 4; ++i) { accg[i] = (floatx4){0,0,0,0}; accu[i] = (floatx4){0,0,0,0}; }

  float4 bv[4];

  auto loadB = [&](int kk) {
    #pragma unroll
    for (int j = 0; j < 4; ++j)
      bv[j] = *(const float4*)&gptr[(size_t)(kk + kb + j) * (2 * I_DIM)];
  };
  auto loadA = [&](int kk, int buf) {
    #pragma unroll
    for (int t = 0; t < 4; ++t)
      gld16(&arow[(size_t)agr[t] * H_DIM + kk + akc], &As[buf][(w * 32 + t * 8) * BK]);
  };
  auto stB = [&](int buf) {
    unsigned int* BsD = (unsigned int*)&Bs[buf][0];
    #pragma unroll
    for (int c = 0; c < 4; ++c) {
      const int r = rb0 + c;
      uint2 d;
      d.x = pk2(bv[0][c], bv[1][c]);
      d.y = pk2(bv[2][c], bv[3][c]);
      *(uint2*)&BsD[r * 32 + ((cwk ^ KEY(r)) << 2) + din] = d;
    }
  };
  auto compute = [&](int cb) {
    #pragma unroll
    for (int kf = 0; kf < 2; ++kf) {
      const int cc = kf * 4 + q;
      const int ca = (cc ^ cswz) * 8;         // A swizzled chunk
      const int cb16 = (cc ^ keyB) * 8;       // B swizzled chunk
      bf16x8 af[4], bg, bu;
      #pragma unroll
      for (int mi = 0; mi < 4; ++mi)
        af[mi] = *(const bf16x8*)&As[cb][(mrow + mi * 16 + lr) * BK + ca];
      bg = *(const bf16x8*)&Bs[cb][rg * BK + cb16];
      bu = *(const bf16x8*)&Bs[cb][(32 + rg) * BK + cb16];
      #pragma unroll
      for (int mi = 0; mi < 4; ++mi) {
        accg[mi] = __builtin_amdgcn_mfma_f32_16x16x32_bf16(af[mi], bg, accg[mi], 0, 0, 0);
        accu[mi] = __builtin_amdgcn_mfma_f32_16x16x32_bf16(af[mi], bu, accu[mi], 0, 0, 0);
      }
    }
  };

  const int nk = H_DIM / BK;   // 16
  // ---- prologue ----
  loadB(0);                    // B(0) -> regs
  loadA(0, 0);                 // A(0) -> As[0]
  stB(0);                      // waits vmcnt(4): B(0) regs ready, A(0) keeps flying
  loadB(BK);                   // B(1) -> regs (in flight across barrier)
  bar_v4();                    // drain A(0); B(1) flying; stB visible
  int cur = 0;

  // ---- main loop ----
  for (int t = 0; t < nk - 1; ++t) {
    loadA((t + 1) * BK, cur ^ 1);            // 4 gld16
    stB(cur ^ 1);                            // pack B(t+1); waits only old B regs
    {
      int t2 = (t + 2 < nk) ? (t + 2) : (nk - 1);
      loadB(t2 * BK);                        // B(t+2) -> regs (clamped tail)
    }
    __builtin_amdgcn_sched_barrier(0);
    compute(cur);
    bar_v4();                                // drain A(t+1); keep B(t+2) flying
    cur ^= 1;
  }
  compute(cur);                              // tail tile (nk-1)

  #pragma unroll
  for (int mi = 0; mi < 4; ++mi)
    #pragma unroll
    for (int r = 0; r < 4; ++r) {
      int row_local = mrow + mi * 16 + q * 4 + r;
      if (row_local >= rows) continue;
      size_t orow = (size_t)(base + row0 + row_local) * I_DIM;
      float g = accg[mi][r], u = accu[mi][r];
      float s = g / (1.0f + __expf(-g)) * u;
      hb[orow + c0 + nhalf * 16 + lr] = f2bf(s);
    }
}

// ---------------- GEMM B: out = h @ Wd (same pipeline, nk=8) ----------------
__launch_bounds__(256, 3)
__global__ void k_gemm_b(const unsigned short* __restrict__ hb,
                         const float* __restrict__ wdn,
                         float* __restrict__ out,
                         const int* __restrict__ counts) {
  __shared__ unsigned short As[2][BM * BK];
  __shared__ unsigned short Bs[2][64 * BK];

  int e, row0, base, cnt;
  if (!tile_info(counts, blockIdx.y, e, row0, base, cnt)) return;
  const int rows = (cnt - row0 < BM) ? (cnt - row0) : BM;
  const int n0 = blockIdx.x * 64;

  const int tid = threadIdx.x;
  const int w = tid >> 6, l = tid & 63;
  const int lr = l & 15, q = l >> 4;
  const int asr = l >> 3;
  const int akc = ((l & 7) ^ asr) * 8;
  const int cswz = lr & 7;

  const int f4 = tid & 15;                    // 4-col chunk within 64
  const int kb = (tid >> 4) * 4;              // 0..60
  const int rb0 = f4 * 4;
  const float* gptr = wdn + (size_t)e * I_DIM * H_DIM + n0 + f4 * 4;
  const int cwk = kb >> 3;
  const int din = (kb >> 1) & 3;

  const int mhalf = w & 1, nhalf = w >> 1;
  const int mrow = mhalf * 64;
  const unsigned short* arow = hb + (size_t)(base + row0) * I_DIM;

  // per-ni B read rows and keys
  const int rn0 = nhalf * 32 + lr;            // ni=0 row
  const int rn1 = nhalf * 32 + 16 + lr;       // ni=1 row
  const int key0 = KEY(rn0), key1 = KEY(rn1);

  int agr[4];
  #pragma unroll
  for (int t = 0; t < 4; ++t) {
    int r = w * 32 + t * 8 + asr;
    agr[t] = (r < rows) ? r : rows - 1;
  }

  floatx4 acc[4][2];
  #pragma unroll
  for (int i = 0; i < 4; ++i)
    #pragma unroll
    for (int j = 0; j < 2; ++j) acc[i][j] = (floatx4){0,0,0,0};

  float4 bv[4];

  auto loadB = [&](int kk) {
    #pragma unroll
    for (int j = 0; j < 4; ++j)
      bv[j] = *(const float4*)&gptr[(size_t)(kk + kb + j) * H_DIM];
  };
  auto loadA = [&](int kk, int buf) {
    #pragma unroll
    for (int t = 0; t < 4; ++t)
      gld16(&arow[(size_t)agr[t] * I_DIM + kk + akc], &As[buf][(w * 32 + t * 8) * BK]);
  };
  auto stB = [&](int buf) {
    unsigned int* BsD = (unsigned int*)&Bs[buf][0];
    #pragma unroll
    for (int c = 0; c < 4; ++c) {
      const int r = rb0 + c;
      uint2 d;
      d.x = pk2(bv[0][c], bv[1][c]);
      d.y = pk2(bv[2][c], bv[3][c]);
      *(uint2*)&BsD[r * 32 + ((cwk ^ KEY(r)) << 2) + din] = d;
    }
  };
  auto compute = [&](int cb) {
    #pragma unroll
    for (int kf = 0; kf < 2; ++kf) {
      const int cc = kf * 4 + q;
      const int ca = (cc ^ cswz) * 8;
      bf16x8 af[4], bf0, bf1;
      #pragma unroll
      for (int mi = 0; mi < 4; ++mi)
        af[mi] = *(const bf16x8*)&As[cb][(mrow + mi * 16 + lr) * BK + ca];
      bf0 = *(const bf16x8*)&Bs[cb][rn0 * BK + (cc ^ key0) * 8];
      bf1 = *(const bf16x8*)&Bs[cb][rn1 * BK + (cc ^ key1) * 8];
      #pragma unroll
      for (int mi = 0; mi < 4; ++mi) {
        acc[mi][0] = __builtin_amdgcn_mfma_f32_16x16x32_bf16(af[mi], bf0, acc[mi][0], 0, 0, 0);
        acc[mi][1] = __builtin_amdgcn_mfma_f32_16x16x32_bf16(af[mi], bf1, acc[mi][1], 0, 0, 0);
      }
    }
  };

  const int nk = I_DIM / BK;   // 8
  loadB(0);
  loadA(0, 0);
  stB(0);
  loadB(BK);
  bar_v4();
  int cur = 0;

  for (int t = 0; t < nk - 1; ++t) {
    loadA((t + 1) * BK, cur ^ 1);
    stB(cur ^ 1);
    {
      int t2 = (t + 2 < nk) ? (t + 2) : (nk - 1);
      loadB(t2 * BK);
    }
    __builtin_amdgcn_sched_barrier(0);
    compute(cur);
    bar_v4();
    cur ^= 1;
  }
  compute(cur);

  #pragma unroll
  for (int mi = 0; mi < 4; ++mi)
    #pragma unroll
    for (int r = 0; r < 4; ++r) {
      int row_local = mrow + mi * 16 + q * 4 + r;
      if (row_local >= rows) continue;
      size_t orow = (size_t)(base + row0 + row_local) * H_DIM;
      #pragma unroll
      for (int ni = 0; ni < 2; ++ni)
        out[orow + n0 + nhalf * 32 + ni * 16 + lr] = acc[mi][ni][r];
    }
}

// ---------------- launch ----------------
extern "C" void kernel_launch(void* const* d_in, const int* in_sizes, int n_in,
                              void* d_out, int out_size, void* d_ws, size_t ws_size,
                              hipStream_t stream) {
  const float* x      = (const float*)d_in[0];
  const float* wgu    = (const float*)d_in[1];
  const float* wdn    = (const float*)d_in[2];
  const int*   counts = (const int*)d_in[3];
  float* out = (float*)d_out;

  unsigned char* ws = (unsigned char*)d_ws;
  unsigned short* xb = (unsigned short*)(ws);            // 8 MB
  unsigned short* hb = (unsigned short*)(ws + 8388608);  // 4 MB

  k_cvt<<<2048, 256, 0, stream>>>(x, xb);
  k_gemm_a<<<dim3(I_DIM / 32, 48), 256, 0, stream>>>(xb, wgu, hb, counts);   // 768 blocks
  k_gemm_b<<<dim3(H_DIM / 64, 48), 256, 0, stream>>>(hb, wdn, out, counts);  // 768 blocks
}